// Round 4
// baseline (261.012 us; speedup 1.0000x reference)
//
#include <hip/hip_runtime.h>
#include <hip/hip_bf16.h>

#define NN 20000        // N_NODES
#define NE 640000       // N_EDGES
#define FEAT 416
#define EPB 64          // edges per block
#define EDGE_BLOCKS (NE / EPB)   // 10000

// d_ws layout: int flag at byte 0 (1 = int32 layout, 2 = int64 layout),
// bb5 floats (NN*15) starting at byte 64.

__global__ __launch_bounds__(256) void prep_kernel(const float* __restrict__ bb,
                                                   const int* __restrict__ ei,
                                                   int* __restrict__ flag,
                                                   float* __restrict__ bb5) {
    int t = blockIdx.x * 256 + threadIdx.x;

    // dtype probe: if edge_index is int64, the high dword of each qword is 0
    // (values in [0, 20000)). With int32 data these are random indices,
    // P(all 64 == 0) ~ (1/20000)^64 ~ 0.
    if (blockIdx.x == 0 && threadIdx.x < 64) {
        int v = ei[2 * threadIdx.x + 1];
        unsigned long long m = __ballot(v != 0);
        if (threadIdx.x == 0) flag[0] = (m == 0ULL) ? 2 : 1;
    }

    if (t < NN) {
        const float* r = bb + (size_t)t * 12;
        float Nx = r[0], Ny = r[1], Nz = r[2];
        float CAx = r[3], CAy = r[4], CAz = r[5];
        float Cx = r[6], Cy = r[7], Cz = r[8];
        float Ox = r[9], Oy = r[10], Oz = r[11];
        float bx = CAx - Nx, by = CAy - Ny, bz = CAz - Nz;
        float cx = Cx - CAx, cy = Cy - CAy, cz = Cz - CAz;
        float ax = by * cz - bz * cy;
        float ay = bz * cx - bx * cz;
        float az = bx * cy - by * cx;
        float vx = -0.58273431f * ax + 0.56802827f * bx - 0.54067466f * cx + CAx;
        float vy = -0.58273431f * ay + 0.56802827f * by - 0.54067466f * cy + CAy;
        float vz = -0.58273431f * az + 0.56802827f * bz - 0.54067466f * cz + CAz;
        float* w = bb5 + (size_t)t * 15;
        w[0] = Nx;  w[1] = Ny;  w[2] = Nz;
        w[3] = CAx; w[4] = CAy; w[5] = CAz;
        w[6] = Cx;  w[7] = Cy;  w[8] = Cz;
        w[9] = Ox;  w[10] = Oy; w[11] = Oz;
        w[12] = vx; w[13] = vy; w[14] = vz;
    }
}

__device__ __forceinline__ void load_idx(const int* __restrict__ ei, int sel, int e,
                                         int& dst, int& src) {
    if (sel == 2) {            // int64 layout: low dword of qword
        dst = ei[2 * e];
        src = ei[2 * (NE + e)];
    } else {                   // int32 layout
        dst = ei[e];
        src = ei[NE + e];
    }
}

__global__ __launch_bounds__(256) void edge_kernel(const int* __restrict__ ei,
                                                   const float* __restrict__ bb5,
                                                   const int* __restrict__ flag,
                                                   float* __restrict__ out) {
    __shared__ float dist[EPB * 25];   // pre-scaled by 0.8 (= 1/sigma)
    __shared__ int sidx[EPB * 2];      // (dst, src) per edge

    const int tid = threadIdx.x;
    const int e0 = blockIdx.x * EPB;

    if (tid < EPB) {
        int dst, src;
        load_idx(ei, flag[0], e0 + tid, dst, src);
        sidx[tid * 2] = dst;
        sidx[tid * 2 + 1] = src;
    }
    __syncthreads();

    // ---- Phase A: EPB*25 distances (one per (edge, atom-pair)), staged in LDS
    for (int item = tid; item < EPB * 25; item += 256) {
        int s = item / 25;
        int p = item - s * 25;
        int i = p / 5;                 // src atom
        int j = p - i * 5;             // dst atom
        int dst = sidx[s * 2], src = sidx[s * 2 + 1];
        const float* S = bb5 + src * 15 + i * 3;
        const float* D = bb5 + dst * 15 + j * 3;
        float dx = S[0] - D[0] + 1e-8f;
        float dy = S[1] - D[1] + 1e-8f;
        float dz = S[2] - D[2] + 1e-8f;
        dist[item] = sqrtf(dx * dx + dy * dy + dz * dz) * 0.8f;
    }

    float4* out4 = reinterpret_cast<float4*>(out) + (size_t)e0 * 104;

    // ---- Phase C: positional embeddings — exactly 256 threads (EPB*4 chunks)
    // angle = (float)(dst-src) * freq_f32 (matches reference product);
    // reduce in double to revolutions, then raw v_sin/v_cos.
    {
        int s = tid >> 2;
        int g = tid & 3;               // 0,1 = cos(f0-3, f4-7); 2,3 = sin
        int dst = sidx[s * 2], src = sidx[s * 2 + 1];
        float d = (float)(dst - src);
        int fb = (g & 1) * 4;
        bool issin = (g >= 2);
        float v[4];
#pragma unroll
        for (int k = 0; k < 4; ++k) {
            int f = fb + k;
            float freq = expf(-(float)f * (float)(9.210340371976184 / 8.0)); // accurate
            float angle = d * freq;                         // f32, matches ref
            double t = (double)angle * 0.15915494309189535; // 1/(2*pi)
            double r = t - rint(t);                         // |r| <= 0.5 revolutions
            float rf = (float)r;
            float val;
            if (issin) {
                asm("v_sin_f32 %0, %1" : "=v"(val) : "v"(rf));
            } else {
                asm("v_cos_f32 %0, %1" : "=v"(val) : "v"(rf));
            }
            v[k] = val;
        }
        out4[s * 104 + 100 + g] = make_float4(v[0], v[1], v[2], v[3]);
    }
    __syncthreads();

    // ---- Phase B: RBF chunks, one float4 per thread, exactly 25 rounds
#pragma unroll
    for (int r = 0; r < 25; ++r) {
        int item = tid + r * 256;
        int s = item / 100;
        int c = item - s * 100;        // chunk within edge's RBF region
        int p = c >> 2;                // pair index
        int g = c & 3;                 // 4-center group
        float a = dist[s * 25 + p];    // broadcast read (4 lanes share)
        int k0 = g * 4;
        float4 rr;
        float u;
        u = a - (float)(k0 + 0) * (16.0f / 15.0f); rr.x = __expf(-(u * u));
        u = a - (float)(k0 + 1) * (16.0f / 15.0f); rr.y = __expf(-(u * u));
        u = a - (float)(k0 + 2) * (16.0f / 15.0f); rr.z = __expf(-(u * u));
        u = a - (float)(k0 + 3) * (16.0f / 15.0f); rr.w = __expf(-(u * u));
        out4[s * 104 + c] = rr;
    }
}

extern "C" void kernel_launch(void* const* d_in, const int* in_sizes, int n_in,
                              void* d_out, int out_size, void* d_ws, size_t ws_size,
                              hipStream_t stream) {
    const float* bb = (const float*)d_in[0];
    const int* ei = (const int*)d_in[1];
    int* flag = (int*)d_ws;
    float* bb5 = (float*)((char*)d_ws + 64);
    float* out = (float*)d_out;

    hipLaunchKernelGGL(prep_kernel, dim3((NN + 255) / 256), dim3(256), 0, stream,
                       bb, ei, flag, bb5);
    hipLaunchKernelGGL(edge_kernel, dim3(EDGE_BLOCKS), dim3(256), 0, stream,
                       ei, bb5, flag, out);
}

// Round 6
// 228.062 us; speedup vs baseline: 1.1445x; 1.1445x over previous
//
#include <hip/hip_runtime.h>
#include <hip/hip_bf16.h>

#define NN 20000        // N_NODES
#define NE 640000       // N_EDGES
#define FEAT 416
#define EPB 16          // edges per block (EPB=64 + unroll-25 regressed: VGPR pressure)
#define EDGE_BLOCKS (NE / EPB)   // 40000

typedef float f32x4 __attribute__((ext_vector_type(4)));   // native vector for NT stores

// d_ws layout: int flag at byte 0 (1 = int32 layout, 2 = int64 layout),
// bb5 floats (NN*15) starting at byte 64.

__global__ __launch_bounds__(256) void prep_kernel(const float* __restrict__ bb,
                                                   const int* __restrict__ ei,
                                                   int* __restrict__ flag,
                                                   float* __restrict__ bb5) {
    int t = blockIdx.x * 256 + threadIdx.x;

    // dtype probe: if edge_index is int64, the high dword of each qword is 0
    // (values in [0, 20000)). With int32 data these are random indices,
    // P(all 64 == 0) ~ (1/20000)^64 ~ 0.
    if (blockIdx.x == 0 && threadIdx.x < 64) {
        int v = ei[2 * threadIdx.x + 1];
        unsigned long long m = __ballot(v != 0);
        if (threadIdx.x == 0) flag[0] = (m == 0ULL) ? 2 : 1;
    }

    if (t < NN) {
        const float* r = bb + (size_t)t * 12;
        float Nx = r[0], Ny = r[1], Nz = r[2];
        float CAx = r[3], CAy = r[4], CAz = r[5];
        float Cx = r[6], Cy = r[7], Cz = r[8];
        float Ox = r[9], Oy = r[10], Oz = r[11];
        float bx = CAx - Nx, by = CAy - Ny, bz = CAz - Nz;
        float cx = Cx - CAx, cy = Cy - CAy, cz = Cz - CAz;
        float ax = by * cz - bz * cy;
        float ay = bz * cx - bx * cz;
        float az = bx * cy - by * cx;
        float vx = -0.58273431f * ax + 0.56802827f * bx - 0.54067466f * cx + CAx;
        float vy = -0.58273431f * ay + 0.56802827f * by - 0.54067466f * cy + CAy;
        float vz = -0.58273431f * az + 0.56802827f * bz - 0.54067466f * cz + CAz;
        float* w = bb5 + (size_t)t * 15;
        w[0] = Nx;  w[1] = Ny;  w[2] = Nz;
        w[3] = CAx; w[4] = CAy; w[5] = CAz;
        w[6] = Cx;  w[7] = Cy;  w[8] = Cz;
        w[9] = Ox;  w[10] = Oy; w[11] = Oz;
        w[12] = vx; w[13] = vy; w[14] = vz;
    }
}

__device__ __forceinline__ void load_idx(const int* __restrict__ ei, int sel, int e,
                                         int& dst, int& src) {
    if (sel == 2) {            // int64 layout: low dword of qword
        dst = ei[2 * e];
        src = ei[2 * (NE + e)];
    } else {                   // int32 layout
        dst = ei[e];
        src = ei[NE + e];
    }
}

__global__ __launch_bounds__(256) void edge_kernel(const int* __restrict__ ei,
                                                   const float* __restrict__ bb5,
                                                   const int* __restrict__ flag,
                                                   float* __restrict__ out) {
    __shared__ float dist[EPB * 25];   // pre-scaled by 0.8 (= 1/sigma)
    __shared__ int sidx[EPB * 2];      // (dst, src) per edge

    const int tid = threadIdx.x;
    const int e0 = blockIdx.x * EPB;

    if (tid < EPB) {
        int dst, src;
        load_idx(ei, flag[0], e0 + tid, dst, src);
        sidx[tid * 2] = dst;
        sidx[tid * 2 + 1] = src;
    }
    __syncthreads();

    // ---- Phase A: 400 distances (one per (edge, atom-pair)), staged in LDS
    for (int item = tid; item < EPB * 25; item += 256) {
        int s = item / 25;
        int p = item - s * 25;
        int i = p / 5;                 // src atom
        int j = p - i * 5;             // dst atom
        int dst = sidx[s * 2], src = sidx[s * 2 + 1];
        const float* S = bb5 + src * 15 + i * 3;
        const float* D = bb5 + dst * 15 + j * 3;
        float dx = S[0] - D[0] + 1e-8f;
        float dy = S[1] - D[1] + 1e-8f;
        float dz = S[2] - D[2] + 1e-8f;
        dist[item] = sqrtf(dx * dx + dy * dy + dz * dz) * 0.8f;
    }

    f32x4* out4 = reinterpret_cast<f32x4*>(out) + (size_t)e0 * 104;

    // ---- Phase C: positional embeddings (threads 0..63)
    // angle = (float)(dst-src) * freq_f32 (matches reference product);
    // reduce in double to revolutions, then raw v_sin/v_cos.
    if (tid < EPB * 4) {
        int s = tid >> 2;
        int g = tid & 3;               // 0,1 = cos(f0-3, f4-7); 2,3 = sin
        int dst = sidx[s * 2], src = sidx[s * 2 + 1];
        float d = (float)(dst - src);
        int fb = (g & 1) * 4;
        bool issin = (g >= 2);
        float v[4];
#pragma unroll
        for (int k = 0; k < 4; ++k) {
            int f = fb + k;
            float freq = expf(-(float)f * (float)(9.210340371976184 / 8.0)); // accurate
            float angle = d * freq;                         // f32, matches ref
            double t = (double)angle * 0.15915494309189535; // 1/(2*pi)
            double r = t - rint(t);                         // |r| <= 0.5 revolutions
            float rf = (float)r;
            float val;
            if (issin) {
                asm("v_sin_f32 %0, %1" : "=v"(val) : "v"(rf));
            } else {
                asm("v_cos_f32 %0, %1" : "=v"(val) : "v"(rf));
            }
            v[k] = val;
        }
        f32x4 r4;
        r4.x = v[0]; r4.y = v[1]; r4.z = v[2]; r4.w = v[3];
        __builtin_nontemporal_store(r4, &out4[s * 104 + 100 + g]);
    }
    __syncthreads();

    // ---- Phase B: RBF chunks, one float4 per thread, fully coalesced, NT stores
    for (int item = tid; item < EPB * 100; item += 256) {
        int s = item / 100;
        int c = item - s * 100;        // chunk within edge's RBF region
        int p = c >> 2;                // pair index
        int g = c & 3;                 // 4-center group
        float a = dist[s * 25 + p];    // broadcast read (4 lanes share)
        int k0 = g * 4;
        f32x4 r;
        float u;
        u = a - (float)(k0 + 0) * (16.0f / 15.0f); r.x = __expf(-(u * u));
        u = a - (float)(k0 + 1) * (16.0f / 15.0f); r.y = __expf(-(u * u));
        u = a - (float)(k0 + 2) * (16.0f / 15.0f); r.z = __expf(-(u * u));
        u = a - (float)(k0 + 3) * (16.0f / 15.0f); r.w = __expf(-(u * u));
        __builtin_nontemporal_store(r, &out4[s * 104 + c]);
    }
}

extern "C" void kernel_launch(void* const* d_in, const int* in_sizes, int n_in,
                              void* d_out, int out_size, void* d_ws, size_t ws_size,
                              hipStream_t stream) {
    const float* bb = (const float*)d_in[0];
    const int* ei = (const int*)d_in[1];
    int* flag = (int*)d_ws;
    float* bb5 = (float*)((char*)d_ws + 64);
    float* out = (float*)d_out;

    hipLaunchKernelGGL(prep_kernel, dim3((NN + 255) / 256), dim3(256), 0, stream,
                       bb, ei, flag, bb5);
    hipLaunchKernelGGL(edge_kernel, dim3(EDGE_BLOCKS), dim3(256), 0, stream,
                       ei, bb5, flag, out);
}

// Round 7
// 213.878 us; speedup vs baseline: 1.2204x; 1.0663x over previous
//
#include <hip/hip_runtime.h>
#include <hip/hip_bf16.h>

#define NN 20000        // N_NODES
#define NE 640000       // N_EDGES
#define FEAT 416
#define EPB 16          // edges per block
#define EDGE_BLOCKS (NE / EPB)   // 40000

typedef float f32x4 __attribute__((ext_vector_type(4)));

__device__ __forceinline__ void load_idx(const int* __restrict__ ei, int sel, int e,
                                         int& dst, int& src) {
    if (sel == 2) {            // int64 layout: low dword of qword
        dst = ei[2 * e];
        src = ei[2 * (NE + e)];
    } else {                   // int32 layout
        dst = ei[e];
        src = ei[NE + e];
    }
}

__global__ __launch_bounds__(256) void fused_kernel(const float* __restrict__ bb,
                                                    const int* __restrict__ ei,
                                                    float* __restrict__ out) {
    __shared__ float rows[2 * EPB][17];   // [even]=dst-node, [odd]=src-node; 15 used
    __shared__ float dist[EPB * 25];      // pre-scaled by 0.8 (= 1/sigma)
    __shared__ int sidx[EPB * 2];         // (dst, src) per edge

    const int tid = threadIdx.x;
    const int e0 = blockIdx.x * EPB;

    // ---- Phase 0 (wave 0 only): dtype probe + row gather + virtual CB
    if (tid < 64) {
        // probe: if edge_index is int64, high dword of each qword is 0
        // (values in [0,20000)); with int32 these are random indices.
        int pv = ei[2 * tid + 1];
        unsigned long long m = __ballot(pv != 0);
        int sel = (m == 0ULL) ? 2 : 1;      // uniform across wave 0

        if (tid < 2 * EPB) {                // 32 node slots (2 per edge)
            int e = e0 + (tid >> 1);
            int dst, src;
            load_idx(ei, sel, e, dst, src);
            int node = (tid & 1) ? src : dst;
            sidx[tid] = node;               // sidx[2s]=dst, sidx[2s+1]=src
            const f32x4* bv = (const f32x4*)bb + (size_t)node * 3;  // 48B rows
            f32x4 v0 = bv[0], v1 = bv[1], v2 = bv[2];
            float Nx = v0.x, Ny = v0.y, Nz = v0.z;
            float CAx = v0.w, CAy = v1.x, CAz = v1.y;
            float Cx = v1.z, Cy = v1.w, Cz = v2.x;
            float Ox = v2.y, Oy = v2.z, Oz = v2.w;
            float bx = CAx - Nx, by = CAy - Ny, bz = CAz - Nz;
            float cx = Cx - CAx, cy = Cy - CAy, cz = Cz - CAz;
            float ax = by * cz - bz * cy;
            float ay = bz * cx - bx * cz;
            float az = bx * cy - by * cx;
            float vx = -0.58273431f * ax + 0.56802827f * bx - 0.54067466f * cx + CAx;
            float vy = -0.58273431f * ay + 0.56802827f * by - 0.54067466f * cy + CAy;
            float vz = -0.58273431f * az + 0.56802827f * bz - 0.54067466f * cz + CAz;
            float* w = rows[tid];
            w[0] = Nx;  w[1] = Ny;  w[2] = Nz;
            w[3] = CAx; w[4] = CAy; w[5] = CAz;
            w[6] = Cx;  w[7] = Cy;  w[8] = Cz;
            w[9] = Ox;  w[10] = Oy; w[11] = Oz;
            w[12] = vx; w[13] = vy; w[14] = vz;
        }
    }
    __syncthreads();

    // ---- Phase A: 400 distances (one per (edge, atom-pair)), staged in LDS
    for (int item = tid; item < EPB * 25; item += 256) {
        int s = item / 25;
        int p = item - s * 25;
        int i = p / 5;                 // src atom
        int j = p - i * 5;             // dst atom
        const float* S = rows[2 * s + 1] + i * 3;
        const float* D = rows[2 * s] + j * 3;
        float dx = S[0] - D[0] + 1e-8f;
        float dy = S[1] - D[1] + 1e-8f;
        float dz = S[2] - D[2] + 1e-8f;
        dist[item] = sqrtf(dx * dx + dy * dy + dz * dz) * 0.8f;
    }

    f32x4* out4 = reinterpret_cast<f32x4*>(out) + (size_t)e0 * 104;

    // ---- Phase C: positional embeddings (threads 0..63)
    // angle = (float)(dst-src) * freq_f32; reduce in double to revolutions,
    // then raw v_sin/v_cos (hardware takes revolutions).
    if (tid < EPB * 4) {
        int s = tid >> 2;
        int g = tid & 3;               // 0,1 = cos(f0-3, f4-7); 2,3 = sin
        int dst = sidx[s * 2], src = sidx[s * 2 + 1];
        float d = (float)(dst - src);
        int fb = (g & 1) * 4;
        bool issin = (g >= 2);
        float v[4];
#pragma unroll
        for (int k = 0; k < 4; ++k) {
            int f = fb + k;
            float freq = expf(-(float)f * (float)(9.210340371976184 / 8.0)); // accurate
            float angle = d * freq;                         // f32, matches ref
            double t = (double)angle * 0.15915494309189535; // 1/(2*pi)
            double r = t - rint(t);                         // |r| <= 0.5 revolutions
            float rf = (float)r;
            float val;
            if (issin) {
                asm("v_sin_f32 %0, %1" : "=v"(val) : "v"(rf));
            } else {
                asm("v_cos_f32 %0, %1" : "=v"(val) : "v"(rf));
            }
            v[k] = val;
        }
        f32x4 r4;
        r4.x = v[0]; r4.y = v[1]; r4.z = v[2]; r4.w = v[3];
        out4[s * 104 + 100 + g] = r4;
    }
    __syncthreads();

    // ---- Phase B: RBF chunks, one float4 per thread, fully coalesced
    for (int item = tid; item < EPB * 100; item += 256) {
        int s = item / 100;
        int c = item - s * 100;        // chunk within edge's RBF region
        int p = c >> 2;                // pair index
        int g = c & 3;                 // 4-center group
        float a = dist[s * 25 + p];    // broadcast read (4 lanes share)
        int k0 = g * 4;
        f32x4 r;
        float u;
        u = a - (float)(k0 + 0) * (16.0f / 15.0f); r.x = __expf(-(u * u));
        u = a - (float)(k0 + 1) * (16.0f / 15.0f); r.y = __expf(-(u * u));
        u = a - (float)(k0 + 2) * (16.0f / 15.0f); r.z = __expf(-(u * u));
        u = a - (float)(k0 + 3) * (16.0f / 15.0f); r.w = __expf(-(u * u));
        out4[s * 104 + c] = r;
    }
}

extern "C" void kernel_launch(void* const* d_in, const int* in_sizes, int n_in,
                              void* d_out, int out_size, void* d_ws, size_t ws_size,
                              hipStream_t stream) {
    const float* bb = (const float*)d_in[0];
    const int* ei = (const int*)d_in[1];
    float* out = (float*)d_out;

    hipLaunchKernelGGL(fused_kernel, dim3(EDGE_BLOCKS), dim3(256), 0, stream,
                       bb, ei, out);
}

// Round 8
// 204.677 us; speedup vs baseline: 1.2752x; 1.0450x over previous
//
#include <hip/hip_runtime.h>
#include <hip/hip_bf16.h>

#define NN 20000        // N_NODES
#define NE 640000       // N_EDGES
#define FEAT 416
#define EPB 16          // edges per block
#define EDGE_BLOCKS (NE / EPB)   // 40000

typedef float f32x4 __attribute__((ext_vector_type(4)));

// d_ws layout: int flag at byte 0 (1 = int32 layout, 2 = int64 layout),
// bb5 floats (NN*15) starting at byte 64.

__global__ __launch_bounds__(256) void prep_kernel(const float* __restrict__ bb,
                                                   const int* __restrict__ ei,
                                                   int* __restrict__ flag,
                                                   float* __restrict__ bb5) {
    int t = blockIdx.x * 256 + threadIdx.x;

    // dtype probe: if edge_index is int64, the high dword of each qword is 0
    // (values in [0, 20000)). With int32 data these are random indices,
    // P(all 64 == 0) ~ (1/20000)^64 ~ 0.
    if (blockIdx.x == 0 && threadIdx.x < 64) {
        int v = ei[2 * threadIdx.x + 1];
        unsigned long long m = __ballot(v != 0);
        if (threadIdx.x == 0) flag[0] = (m == 0ULL) ? 2 : 1;
    }

    if (t < NN) {
        const float* r = bb + (size_t)t * 12;
        float Nx = r[0], Ny = r[1], Nz = r[2];
        float CAx = r[3], CAy = r[4], CAz = r[5];
        float Cx = r[6], Cy = r[7], Cz = r[8];
        float Ox = r[9], Oy = r[10], Oz = r[11];
        float bx = CAx - Nx, by = CAy - Ny, bz = CAz - Nz;
        float cx = Cx - CAx, cy = Cy - CAy, cz = Cz - CAz;
        float ax = by * cz - bz * cy;
        float ay = bz * cx - bx * cz;
        float az = bx * cy - by * cx;
        float vx = -0.58273431f * ax + 0.56802827f * bx - 0.54067466f * cx + CAx;
        float vy = -0.58273431f * ay + 0.56802827f * by - 0.54067466f * cy + CAy;
        float vz = -0.58273431f * az + 0.56802827f * bz - 0.54067466f * cz + CAz;
        float* w = bb5 + (size_t)t * 15;
        w[0] = Nx;  w[1] = Ny;  w[2] = Nz;
        w[3] = CAx; w[4] = CAy; w[5] = CAz;
        w[6] = Cx;  w[7] = Cy;  w[8] = Cz;
        w[9] = Ox;  w[10] = Oy; w[11] = Oz;
        w[12] = vx; w[13] = vy; w[14] = vz;
    }
}

__device__ __forceinline__ void load_idx(const int* __restrict__ ei, int sel, int e,
                                         int& dst, int& src) {
    if (sel == 2) {            // int64 layout: low dword of qword
        dst = ei[2 * e];
        src = ei[2 * (NE + e)];
    } else {                   // int32 layout
        dst = ei[e];
        src = ei[NE + e];
    }
}

__global__ __launch_bounds__(256) void edge_kernel(const int* __restrict__ ei,
                                                   const float* __restrict__ bb5,
                                                   const int* __restrict__ flag,
                                                   float* __restrict__ out) {
    __shared__ float rows[2 * EPB][16];   // [2s]=dst row, [2s+1]=src row; 15 cols used
    __shared__ float dist[EPB * 25];      // pre-scaled by 0.8 (= 1/sigma)
    __shared__ int sidx[EPB * 2];         // (dst, src) per edge

    const int tid = threadIdx.x;
    const int e0 = blockIdx.x * EPB;
    const int sel = flag[0];

    // ---- Phase 0: cooperative row gather, all 256 threads.
    // slot = tid>>3 (32 node slots), 8 lanes per slot load 15 dwords coalesced.
    {
        int slot = tid >> 3;
        int l = tid & 7;
        int e = e0 + (slot >> 1);
        int dst, src;
        load_idx(ei, sel, e, dst, src);
        int node = (slot & 1) ? src : dst;
        if (l == 0) sidx[slot] = node;          // sidx[2s]=dst, sidx[2s+1]=src
        const float* grow = bb5 + (size_t)node * 15;
        rows[slot][l] = grow[l];
        if (l + 8 < 15) rows[slot][l + 8] = grow[l + 8];
    }
    __syncthreads();

    // ---- Phase A: 400 distances (one per (edge, atom-pair)), operands from LDS
    for (int item = tid; item < EPB * 25; item += 256) {
        int s = item / 25;
        int p = item - s * 25;
        int i = p / 5;                 // src atom
        int j = p - i * 5;             // dst atom
        const float* S = rows[2 * s + 1] + i * 3;
        const float* D = rows[2 * s] + j * 3;
        float dx = S[0] - D[0] + 1e-8f;
        float dy = S[1] - D[1] + 1e-8f;
        float dz = S[2] - D[2] + 1e-8f;
        dist[item] = sqrtf(dx * dx + dy * dy + dz * dz) * 0.8f;
    }

    f32x4* out4 = reinterpret_cast<f32x4*>(out) + (size_t)e0 * 104;

    // ---- Phase C: positional embeddings (threads 0..63)
    // angle = (float)(dst-src) * freq_f32; reduce in double to revolutions,
    // then raw v_sin/v_cos (hardware takes revolutions).
    if (tid < EPB * 4) {
        int s = tid >> 2;
        int g = tid & 3;               // 0,1 = cos(f0-3, f4-7); 2,3 = sin
        int dst = sidx[s * 2], src = sidx[s * 2 + 1];
        float d = (float)(dst - src);
        int fb = (g & 1) * 4;
        bool issin = (g >= 2);
        float v[4];
#pragma unroll
        for (int k = 0; k < 4; ++k) {
            int f = fb + k;
            float freq = expf(-(float)f * (float)(9.210340371976184 / 8.0)); // accurate
            float angle = d * freq;                         // f32, matches ref
            double t = (double)angle * 0.15915494309189535; // 1/(2*pi)
            double r = t - rint(t);                         // |r| <= 0.5 revolutions
            float rf = (float)r;
            float val;
            if (issin) {
                asm("v_sin_f32 %0, %1" : "=v"(val) : "v"(rf));
            } else {
                asm("v_cos_f32 %0, %1" : "=v"(val) : "v"(rf));
            }
            v[k] = val;
        }
        f32x4 r4;
        r4.x = v[0]; r4.y = v[1]; r4.z = v[2]; r4.w = v[3];
        out4[s * 104 + 100 + g] = r4;
    }
    __syncthreads();

    // ---- Phase B: RBF chunks, one float4 per thread, fully coalesced
    for (int item = tid; item < EPB * 100; item += 256) {
        int s = item / 100;
        int c = item - s * 100;        // chunk within edge's RBF region
        int p = c >> 2;                // pair index
        int g = c & 3;                 // 4-center group
        float a = dist[s * 25 + p];    // broadcast read (4 lanes share)
        int k0 = g * 4;
        f32x4 r;
        float u;
        u = a - (float)(k0 + 0) * (16.0f / 15.0f); r.x = __expf(-(u * u));
        u = a - (float)(k0 + 1) * (16.0f / 15.0f); r.y = __expf(-(u * u));
        u = a - (float)(k0 + 2) * (16.0f / 15.0f); r.z = __expf(-(u * u));
        u = a - (float)(k0 + 3) * (16.0f / 15.0f); r.w = __expf(-(u * u));
        out4[s * 104 + c] = r;
    }
}

extern "C" void kernel_launch(void* const* d_in, const int* in_sizes, int n_in,
                              void* d_out, int out_size, void* d_ws, size_t ws_size,
                              hipStream_t stream) {
    const float* bb = (const float*)d_in[0];
    const int* ei = (const int*)d_in[1];
    int* flag = (int*)d_ws;
    float* bb5 = (float*)((char*)d_ws + 64);
    float* out = (float*)d_out;

    hipLaunchKernelGGL(prep_kernel, dim3((NN + 255) / 256), dim3(256), 0, stream,
                       bb, ei, flag, bb5);
    hipLaunchKernelGGL(edge_kernel, dim3(EDGE_BLOCKS), dim3(256), 0, stream,
                       ei, bb5, flag, out);
}